// Round 1
// baseline (161.028 us; speedup 1.0000x reference)
//
#include <hip/hip_runtime.h>
#include <hip/hip_bf16.h>
#include <stdint.h>
#include <stddef.h>

// ContrastiveLoss: N=4096 pairs, D=768.
// loss = mean over NxN of (1-gt)*d2 + gt*max(2-sqrt(d2),0)^2
// d2 = sa[i]+sb[j]-2*dot(i,j)+2e-6*(ra[i]-rb[j])+768e-12, clamped at 0.
// Strategy: exact fp32 row stats + bf16 MFMA for the dot matrix, fused epilogue.

#define NROWS 4096
#define DIM   768
#define BM    128
#define BN    128
#define BK    32
#define MARGIN 2.0f
#define EPSV   1e-6f

typedef __bf16 bf16_t;
typedef bf16_t bf16x8 __attribute__((ext_vector_type(8)));
typedef float  f32x4  __attribute__((ext_vector_type(4)));

// ---------------- prep: bf16 cast + exact row sums / sum-of-squares ---------
__global__ __launch_bounds__(256) void prep_kernel(
    const float* __restrict__ A, const float* __restrict__ B,
    bf16_t* __restrict__ Ab, bf16_t* __restrict__ Bb,
    float* __restrict__ sa, float* __restrict__ sb,
    float* __restrict__ ra, float* __restrict__ rb)
{
    const int row  = blockIdx.x;
    const int isB  = blockIdx.y;
    const float* X = isB ? B : A;
    bf16_t* Xb     = isB ? Bb : Ab;
    float* sdst    = isB ? sb : sa;
    float* rdst    = isB ? rb : ra;

    const int t = threadIdx.x;
    const float* xr = X + (size_t)row * DIM;
    float v0 = xr[t], v1 = xr[t + 256], v2 = xr[t + 512];
    bf16_t* xb = Xb + (size_t)row * DIM;
    xb[t]       = (bf16_t)v0;
    xb[t + 256] = (bf16_t)v1;
    xb[t + 512] = (bf16_t)v2;

    float sum = v0 + v1 + v2;
    float sq  = v0 * v0 + v1 * v1 + v2 * v2;
    #pragma unroll
    for (int off = 32; off > 0; off >>= 1) {
        sum += __shfl_down(sum, off);
        sq  += __shfl_down(sq,  off);
    }
    __shared__ float red[8];
    const int wave = t >> 6;
    if ((t & 63) == 0) { red[wave] = sum; red[4 + wave] = sq; }
    __syncthreads();
    if (t == 0) {
        rdst[row] = (red[0] + red[1]) + (red[2] + red[3]);
        sdst[row] = (red[4] + red[5]) + (red[6] + red[7]);
    }
}

// ---------------- fused GEMM + loss ----------------------------------------
// 128x128 tile per 256-thread block (4 waves, each 64x64 = 4x4 MFMA 16x16x32).
// global_load_lds width-16 staging; k-chunks XOR-swizzled by (row&3) so
// fragment ds_read_b128s land 2-way max on banks.
__global__ __launch_bounds__(256) void loss_kernel(
    const bf16_t* __restrict__ A, const bf16_t* __restrict__ B,
    const float* __restrict__ sa, const float* __restrict__ sb,
    const float* __restrict__ ra, const float* __restrict__ rb,
    const int* __restrict__ gt, float* __restrict__ out)
{
    __shared__ __align__(16) bf16_t As[BM * BK];
    __shared__ __align__(16) bf16_t Bs[BN * BK];
    __shared__ float redp[4];

    const int tid  = threadIdx.x;
    const int wave = tid >> 6;
    const int lane = tid & 63;
    const int m0 = blockIdx.y * BM;
    const int n0 = blockIdx.x * BN;

    f32x4 acc[4][4] = {};

    // staging: lane -> (row-in-16-seg, swizzled k-chunk of 8 bf16)
    const int lrow   = lane >> 2;              // 0..15
    const int kchunk = (lane & 3) ^ (lrow & 3); // xor swizzle

    const int fr = lane & 15;        // frag row (A) / col-row (B)
    const int q  = lane >> 4;        // k-quad
    const int wm = (wave >> 1) * 64;
    const int wn = (wave & 1) * 64;
    const int slot = (q ^ (fr & 3)) * 8; // de-swizzled k slot for reads

    for (int k0 = 0; k0 < DIM; k0 += BK) {
        __syncthreads();   // prev iter's LDS reads done
        #pragma unroll
        for (int t = 0; t < 2; ++t) {
            const int seg  = wave + 4 * t;          // wave-uniform
            const int grow = seg * 16 + lrow;
            const bf16_t* ga = A + (size_t)(m0 + grow) * DIM + k0 + kchunk * 8;
            const bf16_t* gb = B + (size_t)(n0 + grow) * DIM + k0 + kchunk * 8;
            __builtin_amdgcn_global_load_lds(
                (const __attribute__((address_space(1))) void*)ga,
                (__attribute__((address_space(3))) void*)(As + seg * 16 * BK),
                16, 0, 0);
            __builtin_amdgcn_global_load_lds(
                (const __attribute__((address_space(1))) void*)gb,
                (__attribute__((address_space(3))) void*)(Bs + seg * 16 * BK),
                16, 0, 0);
        }
        __syncthreads();   // staging complete

        bf16x8 af[4], bfrag[4];
        #pragma unroll
        for (int i = 0; i < 4; ++i) {
            af[i]    = *(const bf16x8*)(As + (wm + i * 16 + fr) * BK + slot);
            bfrag[i] = *(const bf16x8*)(Bs + (wn + i * 16 + fr) * BK + slot);
        }
        #pragma unroll
        for (int mi = 0; mi < 4; ++mi)
            #pragma unroll
            for (int ni = 0; ni < 4; ++ni)
                acc[mi][ni] = __builtin_amdgcn_mfma_f32_16x16x32_bf16(
                    af[mi], bfrag[ni], acc[mi][ni], 0, 0, 0);
    }

    // ---- fused epilogue: C/D layout col=lane&15, row=(lane>>4)*4+reg ----
    const int cq = lane & 15;
    const int rq = (lane >> 4) * 4;

    float sbv[4], rbv[4];
    #pragma unroll
    for (int ni = 0; ni < 4; ++ni) {
        const int col = n0 + wn + ni * 16 + cq;
        sbv[ni] = sb[col];
        rbv[ni] = rb[col];
    }

    float local = 0.0f;
    #pragma unroll
    for (int mi = 0; mi < 4; ++mi) {
        #pragma unroll
        for (int rr = 0; rr < 4; ++rr) {
            const int row = m0 + wm + mi * 16 + rq + rr;
            const float sav = sa[row];
            const float rav = ra[row];
            const int* gtr = gt + (size_t)row * NROWS + n0 + wn + cq;
            #pragma unroll
            for (int ni = 0; ni < 4; ++ni) {
                const float dot = acc[mi][ni][rr];
                float sqv = sav + sbv[ni] - 2.0f * dot
                          + (2.0f * EPSV) * (rav - rbv[ni])
                          + (float)DIM * EPSV * EPSV;
                float msq  = fmaxf(sqv, 0.0f);
                float dist = sqrtf(msq);
                float h    = fmaxf(MARGIN - dist, 0.0f);
                const int lbl = gtr[ni * 16];
                local += lbl ? (h * h) : msq;
            }
        }
    }

    #pragma unroll
    for (int off = 32; off > 0; off >>= 1) local += __shfl_down(local, off);
    if (lane == 0) redp[wave] = local;
    __syncthreads();
    if (tid == 0) {
        const float s = (redp[0] + redp[1]) + (redp[2] + redp[3]);
        atomicAdd(out, s * (1.0f / (4096.0f * 4096.0f)));
    }
}

// ---------------------------------------------------------------------------
extern "C" void kernel_launch(void* const* d_in, const int* in_sizes, int n_in,
                              void* d_out, int out_size, void* d_ws, size_t ws_size,
                              hipStream_t stream)
{
    const float* A  = (const float*)d_in[0];
    const float* B  = (const float*)d_in[1];
    const int*   gt = (const int*)d_in[2];
    float* out = (float*)d_out;

    char* ws = (char*)d_ws;
    const size_t NB = (size_t)NROWS * DIM * sizeof(bf16_t); // 6,291,456
    bf16_t* Ab = (bf16_t*)(ws);
    bf16_t* Bb = (bf16_t*)(ws + NB);
    float* sa = (float*)(ws + 2 * NB);
    float* sb = (float*)(ws + 2 * NB + 16384);
    float* ra = (float*)(ws + 2 * NB + 32768);
    float* rb = (float*)(ws + 2 * NB + 49152);

    hipMemsetAsync(d_out, 0, sizeof(float) * (size_t)out_size, stream);
    prep_kernel<<<dim3(NROWS, 2), 256, 0, stream>>>(A, B, Ab, Bb, sa, sb, ra, rb);
    loss_kernel<<<dim3(NROWS / BN, NROWS / BM), 256, 0, stream>>>(
        Ab, Bb, sa, sb, ra, rb, gt, out);
}